// Round 3
// baseline (225.369 us; speedup 1.0000x reference)
//
#include <hip/hip_runtime.h>

// SequenceGroupAggregating: out[b,a,:] = mean_{s: group_by[b,s]==a} x[b,s,:]
// group_by sorted along S -> each group is a contiguous segment [start,end).
//
// Phase 1: one thread per (b,a) binary-searches the segment bounds (writes both
//          fields always -> no memset needed; empty groups get start==end).
// Phase 2: one block per (8 consecutive groups, b). 2048 blocks = 8 blocks/CU
//          x 4 waves = 32 waves/CU (full residency, single round). All 8 bounds
//          preloaded (independent loads), then 8 independent segment-sum streams
//          per thread. Segments of consecutive groups are contiguous rows ->
//          pure streaming. Ideal: 128 MB read + 64 MB write ~= 31 us.

constexpr int AG = 8;  // groups per block (A % AG == 0)

__global__ __launch_bounds__(256) void seg_bounds_kernel(
    const int* __restrict__ gb,     // (B, S) sorted along S
    int2*      __restrict__ bounds, // (B, A) {start, end}
    int S, int A) {
  const int b = blockIdx.y;
  const int a = blockIdx.x * blockDim.x + threadIdx.x;
  if (a >= A) return;
  const int* __restrict__ g = gb + (size_t)b * S;
  int lo = 0, hi = S;
  while (lo < hi) { int m = (lo + hi) >> 1; if (g[m] < a) lo = m + 1; else hi = m; }
  const int start = lo;
  hi = S;
  while (lo < hi) { int m = (lo + hi) >> 1; if (g[m] <= a) lo = m + 1; else hi = m; }
  bounds[(size_t)b * A + a] = make_int2(start, lo);
}

__global__ __launch_bounds__(256) void seq_group_agg_kernel(
    const float* __restrict__ x,       // (B, S, H)
    const int2*  __restrict__ bounds,  // (B, A)
    float*       __restrict__ out,     // (B, A, H)
    int S, int H4, int A) {
  const int b  = blockIdx.y;
  const int a0 = blockIdx.x * AG;

  // Preload all AG bounds (independent -> overlapped latency).
  int2 se[AG];
#pragma unroll
  for (int j = 0; j < AG; ++j) se[j] = bounds[(size_t)b * A + a0 + j];

  const float4* __restrict__ xb = (const float4*)x + (size_t)b * S * H4;

  for (int h4 = threadIdx.x; h4 < H4; h4 += blockDim.x) {
    float4* __restrict__ ob = (float4*)out + ((size_t)b * A + a0) * H4 + h4;
#pragma unroll
    for (int j = 0; j < AG; ++j) {
      const int start = se[j].x, end = se[j].y;
      const int cnt = end - start;
      const float scale = (cnt > 0) ? (1.0f / (float)cnt) : 0.0f;
      float4 acc = make_float4(0.f, 0.f, 0.f, 0.f);
      for (int s = start; s < end; ++s) {
        const float4 v = xb[(size_t)s * H4 + h4];
        acc.x += v.x; acc.y += v.y; acc.z += v.z; acc.w += v.w;
      }
      acc.x *= scale; acc.y *= scale; acc.z *= scale; acc.w *= scale;
      ob[(size_t)j * H4] = acc;  // coalesced; explicit zeros for empty groups
    }
  }
}

extern "C" void kernel_launch(void* const* d_in, const int* in_sizes, int n_in,
                              void* d_out, int out_size, void* d_ws, size_t ws_size,
                              hipStream_t stream) {
  const float* x  = (const float*)d_in[0];
  const int*   gb = (const int*)d_in[1];
  float*       out = (float*)d_out;

  const int BS = in_sizes[1];        // B*S = 32768
  const int H  = in_sizes[0] / BS;   // 1024
  const int A  = 1024;               // agg_step (fixed by setup_inputs)
  const int B  = (out_size / H) / A; // 16
  const int S  = BS / B;             // 2048

  int2* bounds = (int2*)d_ws;        // B*A*8 = 128 KB scratch

  dim3 g1((A + 255) / 256, B);
  seg_bounds_kernel<<<g1, 256, 0, stream>>>(gb, bounds, S, A);

  dim3 g2(A / AG, B);
  seq_group_agg_kernel<<<g2, 256, 0, stream>>>(x, bounds, out, S, H / 4, A);
}

// Round 4
// 210.167 us; speedup vs baseline: 1.0723x; 1.0723x over previous
//
#include <hip/hip_runtime.h>

// SequenceGroupAggregating: out[b,a,:] = mean_{s: group_by[b,s]==a} x[b,s,:]
// group_by sorted along S -> each group is a contiguous segment [start,end).
//
// Phase 1: one thread per (b,a) binary-searches segment bounds (writes both
//          fields always -> empty groups get start==end; no memset needed).
// Phase 2: one block per (2 consecutive groups, b) = 8192 blocks. One int4
//          bounds load per thread, then 2 independent segment-sum streams
//          (avg ~2 rows each). Nontemporal loads on x (read-once) and
//          nontemporal stores on out (write-once, never re-read) keep the
//          64 MB output stream from write-allocating in L2 against the
//          128 MB x read stream. Floor: 192 MB ≈ 31 µs at 6.3 TB/s.

constexpr int AG = 2;  // groups per block (A % AG == 0)

typedef float v4f __attribute__((ext_vector_type(4)));

__global__ __launch_bounds__(256) void seg_bounds_kernel(
    const int* __restrict__ gb,     // (B, S) sorted along S
    int2*      __restrict__ bounds, // (B, A) {start, end}
    int S, int A) {
  const int b = blockIdx.y;
  const int a = blockIdx.x * blockDim.x + threadIdx.x;
  if (a >= A) return;
  const int* __restrict__ g = gb + (size_t)b * S;
  int lo = 0, hi = S;
  while (lo < hi) { int m = (lo + hi) >> 1; if (g[m] < a) lo = m + 1; else hi = m; }
  const int start = lo;
  hi = S;
  while (lo < hi) { int m = (lo + hi) >> 1; if (g[m] <= a) lo = m + 1; else hi = m; }
  bounds[(size_t)b * A + a] = make_int2(start, lo);
}

__global__ __launch_bounds__(256) void seq_group_agg_kernel(
    const float* __restrict__ x,       // (B, S, H)
    const int2*  __restrict__ bounds,  // (B, A)
    float*       __restrict__ out,     // (B, A, H)
    int S, int H4, int A) {
  const int b  = blockIdx.y;
  const int a0 = blockIdx.x * AG;

  // One 16B load fetches both groups' bounds (broadcast across the block).
  int2 se[AG];
#pragma unroll
  for (int j = 0; j < AG; ++j) se[j] = bounds[(size_t)b * A + a0 + j];

  const v4f* __restrict__ xb = (const v4f*)x + (size_t)b * S * H4;
  const int h4 = threadIdx.x;  // H4 == blockDim.x == 256

  v4f acc[AG];
  float scale[AG];
#pragma unroll
  for (int j = 0; j < AG; ++j) {
    const int cnt = se[j].y - se[j].x;
    scale[j] = (cnt > 0) ? (1.0f / (float)cnt) : 0.0f;
    acc[j] = (v4f)(0.0f);
  }
  // Two independent segment streams -> overlapped load latency.
#pragma unroll
  for (int j = 0; j < AG; ++j) {
    for (int s = se[j].x; s < se[j].y; ++s) {
      acc[j] += __builtin_nontemporal_load(xb + (size_t)s * H4 + h4);
    }
  }
  v4f* __restrict__ ob = (v4f*)out + ((size_t)b * A + a0) * H4 + h4;
#pragma unroll
  for (int j = 0; j < AG; ++j) {
    __builtin_nontemporal_store(acc[j] * scale[j], ob + (size_t)j * H4);
  }
}

extern "C" void kernel_launch(void* const* d_in, const int* in_sizes, int n_in,
                              void* d_out, int out_size, void* d_ws, size_t ws_size,
                              hipStream_t stream) {
  const float* x  = (const float*)d_in[0];
  const int*   gb = (const int*)d_in[1];
  float*       out = (float*)d_out;

  const int BS = in_sizes[1];        // B*S = 32768
  const int H  = in_sizes[0] / BS;   // 1024
  const int A  = 1024;               // agg_step (fixed by setup_inputs)
  const int B  = (out_size / H) / A; // 16
  const int S  = BS / B;             // 2048

  int2* bounds = (int2*)d_ws;        // B*A*8 = 128 KB scratch

  dim3 g1((A + 255) / 256, B);
  seg_bounds_kernel<<<g1, 256, 0, stream>>>(gb, bounds, S, A);

  dim3 g2(A / AG, B);
  seq_group_agg_kernel<<<g2, 256, 0, stream>>>(x, bounds, out, S, H / 4, A);
}